// Round 5
// baseline (1977.373 us; speedup 1.0000x reference)
//
#include <hip/hip_runtime.h>

// SineLSTM: 2-layer LSTM (H=50), B=512 independent rows, one row per block.
// R7: mod-4 K-split. Evidence R2/R5/R6: LDS broadcast return-BW is the wall
// (~312 b128 broadcasts/CU-step = ~3750cy = measured step time; barrier count
// 3->1 changed nothing). Broadcasts don't dedupe (64 copies through the
// return crossbar). Fix: wave w computes PARTIAL gate dots over k=w(mod 4)
// for all 200 rows; partials cross waves via LDS as spread traffic (8 b32
// writes + 8 b32 reads per wave-step, ~37KB/CU-step vs 320KB). Wave w needs
// only h[k=w(4)] (13 values), produced in-wave (unit u updated by wave u&3)
// and broadcast ONCE per value via v_readlane->SGPR; dots use SGPR operands
// (zero per-use cost; unlike R4's per-use readlane).
// NUMERICS BIT-IDENTICAL to R5: its a0..a3 accumulators ARE the k-mod-4
// classes; wave0 seeds b1+xin*wih1 / b2; slices ascend; wi2-then-wh2 order;
// gather combines (p0+p2)+(p1+p3); activations/quad-DPP/output trees are
// R6's proven code.

#define Hh   50
#define TLEN 1024     // teacher-forced sequence length (setup_inputs fixed)

__device__ __forceinline__ float fast_sigmoid(float v) {
    return 1.0f / (1.0f + __expf(-v));
}
__device__ __forceinline__ float fast_tanh(float v) {
    // 1 - 2/(e^{2v}+1); saturates correctly for |v| large
    return 1.0f - 2.0f / (__expf(2.0f * v) + 1.0f);
}
// wave-uniform broadcast of lane k's value through an SGPR
__device__ __forceinline__ float rl(float v, int k) {
    return __int_as_float(__builtin_amdgcn_readlane(__float_as_int(v), k));
}

extern "C" __global__ __launch_bounds__(256, 2)
void sine_lstm_kernel(const float* __restrict__ x,
                      const float* __restrict__ W_ih1,
                      const float* __restrict__ W_hh1,
                      const float* __restrict__ b_ih1,
                      const float* __restrict__ b_hh1,
                      const float* __restrict__ W_ih2,
                      const float* __restrict__ W_hh2,
                      const float* __restrict__ b_ih2,
                      const float* __restrict__ b_hh2,
                      const float* __restrict__ W_lin,
                      const float* __restrict__ b_lin,
                      const int*   __restrict__ predict_p,
                      float* __restrict__ out,
                      int T)
{
    __shared__ __align__(16) float x_lds[TLEN];
    __shared__ __align__(16) float gp1[4][256];   // [k-slice][gate row] partials
    __shared__ __align__(16) float gp2[4][256];
    __shared__ __align__(16) float h2l[2][64];    // ping-pong h2 for output dots

    const int tid = threadIdx.x;
    const int wv  = tid >> 6;              // wave = k-residue (and unit-residue)
    const int ln  = tid & 63;
    const int b   = blockIdx.x;            // one batch row per block
    const int predict = *predict_p;
    const int S = T + predict;

    // ---- stage x row into LDS (coalesced) ----
    for (int i = tid; i < TLEN; i += 256)
        x_lds[i] = x[(size_t)b * T + i];
    if (tid < 128) ((float*)h2l)[tid] = 0.0f;

    // ---- partial-dot rows: lane ln owns rows j = ln+64m (m=0..2; +192 if ln<8)
    //      k-slice: k = 4i+wv, i=0..12 (zero-padded where k>=50 / row invalid)
    float wp1[4][13], wpi2[4][13], wph2[4][13];
    float b1r[4], wihr[4], b2r[4];
    #pragma unroll
    for (int m = 0; m < 4; ++m) {
        const int j  = ln + 64 * m;
        const bool rv = (j < 200);
        const int jc = rv ? j : 0;
        b1r[m]  = b_ih1[jc] + b_hh1[jc];
        wihr[m] = W_ih1[jc];
        b2r[m]  = b_ih2[jc] + b_hh2[jc];
        #pragma unroll
        for (int i = 0; i < 13; ++i) {
            const int k = 4 * i + wv;
            const bool kv = rv && (k < Hh);
            const int kc = (k < Hh) ? k : 0;
            wp1[m][i]  = kv ? W_hh1[jc * Hh + kc] : 0.0f;
            wpi2[m][i] = kv ? W_ih2[jc * Hh + kc] : 0.0f;
            wph2[m][i] = kv ? W_hh2[jc * Hh + kc] : 0.0f;
        }
    }

    // ---- gather mapping: lane = 4*iu+q handles gate q of unit u = 4*iu+wv ----
    const int iu = ln >> 2, q = ln & 3;
    const int u  = 4 * iu + wv;
    const bool gact = (iu < 13) && (u < Hh);
    const int  grow = q * Hh + u;              // partial-row index to gather
    const int  growc = gact ? grow : 0;
    const bool lead = gact && (q == 0);        // owns unit u's c/h

    const float wlin_l = (ln < Hh) ? W_lin[ln] : 0.0f;
    const float blin   = b_lin[0];

    float c1r = 0.0f, c2r = 0.0f;              // lead-private cell states
    float h1own = 0.0f, h2own = 0.0f;          // lead-held h (0 on other lanes)
    float sh1[13], sh2[13];                    // wave-uniform h slices (SGPRs)
    #pragma unroll
    for (int i = 0; i < 13; ++i) { sh1[i] = 0.0f; sh2[i] = 0.0f; }
    float o_reg = 0.0f;

    __syncthreads();
    float xin = x_lds[0];

    for (int s = 0; s < S; ++s) {
        const int cur = s & 1, prv = cur ^ 1;

        // ======== G1 partials: p_m = seed + sum_{k=4i+wv} W_hh1[j][k]*h1[k] ====
        {
            float p0, p1, p2, p3;
            if (wv == 0) {   // wave0's partial is R5's a0: seeded b1 + xin*wih1
                p0 = b1r[0] + xin * wihr[0]; p1 = b1r[1] + xin * wihr[1];
                p2 = b1r[2] + xin * wihr[2]; p3 = b1r[3] + xin * wihr[3];
            } else { p0 = p1 = p2 = p3 = 0.0f; }
            #pragma unroll
            for (int i = 0; i < 13; ++i) {
                p0 += wp1[0][i] * sh1[i];
                p1 += wp1[1][i] * sh1[i];
                p2 += wp1[2][i] * sh1[i];
                p3 += wp1[3][i] * sh1[i];
            }
            gp1[wv][ln]       = p0;
            gp1[wv][ln + 64]  = p1;
            gp1[wv][ln + 128] = p2;
            if (ln < 8) gp1[wv][ln + 192] = p3;
        }
        __syncthreads();   // B1: gp1 complete

        // ---- wave3: deferred output for step s-1 (teacher range) ----
        if (wv == 3 && s > 0 && s < T) {
            float part = (ln < Hh) ? h2l[prv][ln] * wlin_l : 0.0f;
            #pragma unroll
            for (int off = 32; off > 0; off >>= 1)
                part += __shfl_down(part, off);
            if (ln == 0) out[(size_t)b * S + (s - 1)] = part + blin;
        }

        // ======== U1: gather partials, quad exchange, lead updates unit u ======
        {
            float g  = (gp1[0][growc] + gp1[2][growc]) + (gp1[1][growc] + gp1[3][growc]);
            float v1 = __shfl_xor(g, 1);   // f-gate (q=1)
            float v2 = __shfl_xor(g, 2);   // g-gate (q=2)
            float v3 = __shfl_xor(g, 3);   // o-gate (q=3)
            if (lead) {                    // g = i-gate on lead
                float cn = fast_sigmoid(v1) * c1r + fast_sigmoid(g) * fast_tanh(v2);
                c1r = cn;
                h1own = fast_sigmoid(v3) * fast_tanh(cn);
            }
        }
        #pragma unroll
        for (int i = 0; i < 13; ++i) sh1[i] = rl(h1own, 4 * i);   // h1 slice -> SGPRs

        // ======== G2 partials: seed(b2) + wi2-slice then wh2-slice (R5 order) ==
        {
            float p0, p1, p2, p3;
            if (wv == 0) { p0 = b2r[0]; p1 = b2r[1]; p2 = b2r[2]; p3 = b2r[3]; }
            else         { p0 = p1 = p2 = p3 = 0.0f; }
            #pragma unroll
            for (int i = 0; i < 13; ++i) {
                p0 += wpi2[0][i] * sh1[i];
                p1 += wpi2[1][i] * sh1[i];
                p2 += wpi2[2][i] * sh1[i];
                p3 += wpi2[3][i] * sh1[i];
            }
            #pragma unroll
            for (int i = 0; i < 13; ++i) {
                p0 += wph2[0][i] * sh2[i];
                p1 += wph2[1][i] * sh2[i];
                p2 += wph2[2][i] * sh2[i];
                p3 += wph2[3][i] * sh2[i];
            }
            gp2[wv][ln]       = p0;
            gp2[wv][ln + 64]  = p1;
            gp2[wv][ln + 128] = p2;
            if (ln < 8) gp2[wv][ln + 192] = p3;
        }
        __syncthreads();   // B2: gp2 complete

        // ======== U2: gather, quad exchange, lead updates; publish h2 ========
        {
            float g  = (gp2[0][growc] + gp2[2][growc]) + (gp2[1][growc] + gp2[3][growc]);
            float v1 = __shfl_xor(g, 1);
            float v2 = __shfl_xor(g, 2);
            float v3 = __shfl_xor(g, 3);
            if (lead) {
                float cn = fast_sigmoid(v1) * c2r + fast_sigmoid(g) * fast_tanh(v2);
                c2r = cn;
                h2own = fast_sigmoid(v3) * fast_tanh(cn);
                h2l[cur][u] = h2own;
            }
        }
        #pragma unroll
        for (int i = 0; i < 13; ++i) sh2[i] = rl(h2own, 4 * i);   // h2 slice -> SGPRs

        // ======== transition + predict: o feeds next step's input ========
        if (s >= T - 1) {
            __syncthreads();   // B3: h2l[cur] complete
            float part = (ln < Hh) ? h2l[cur][ln] * wlin_l : 0.0f;
            #pragma unroll
            for (int off = 32; off > 0; off >>= 1)
                part += __shfl_down(part, off);
            float tot = __shfl(part, 0);
            o_reg = tot + blin;
            if (wv == 3 && ln == 0) out[(size_t)b * S + s] = o_reg;
        }
        xin = (s + 1 < T) ? x_lds[s + 1] : o_reg;
        // Hazard audit:
        //  gp1: W(s,pre-B1) -> R(s,B1..B2). WAR: R(s) done by B2(s); W(s+1) after.
        //  gp2: W(s,B1..B2) -> R(s,post-B2). WAR: R(s) done by B1(s+1); W(s+1) after.
        //  h2l[cur]: W(s,post-B2) -> R deferred(s+1,post-B1(s+1)) / immediate(s,post-B3).
        //  WAR h2l: prior readers of buffer cur(s) finished by B2(s-1)/B1(s).
    }
}

extern "C" void kernel_launch(void* const* d_in, const int* in_sizes, int n_in,
                              void* d_out, int out_size, void* d_ws, size_t ws_size,
                              hipStream_t stream) {
    const float* x      = (const float*)d_in[0];
    const float* W_ih1  = (const float*)d_in[1];
    const float* W_hh1  = (const float*)d_in[2];
    const float* b_ih1  = (const float*)d_in[3];
    const float* b_hh1  = (const float*)d_in[4];
    const float* W_ih2  = (const float*)d_in[5];
    const float* W_hh2  = (const float*)d_in[6];
    const float* b_ih2  = (const float*)d_in[7];
    const float* b_hh2  = (const float*)d_in[8];
    const float* W_lin  = (const float*)d_in[9];
    const float* b_lin  = (const float*)d_in[10];
    const int*   pred   = (const int*)d_in[11];
    float* out = (float*)d_out;

    const int B = 512;                 // fixed by setup_inputs
    const int T = in_sizes[0] / B;     // 1024

    dim3 grid(B), block(256);
    hipLaunchKernelGGL(sine_lstm_kernel, grid, block, 0, stream,
                       x, W_ih1, W_hh1, b_ih1, b_hh1,
                       W_ih2, W_hh2, b_ih2, b_hh2,
                       W_lin, b_lin, pred, out, T);
}